// Round 5
// baseline (900.045 us; speedup 1.0000x reference)
//
#include <hip/hip_runtime.h>
#include <stdint.h>
#include <math.h>

#define N_NODES   100000
#define N_EDGES   1600000
#define NFEAT     100
#define HIDDEN    32
#define OUTC      2

#define BUCK_BITS 7
#define BUCK_SZ   128                       // nodes per bucket
#define NBUCK     782                       // ceil(100000/128)

// ---------------------------------------------------------------------------
// JAX threefry2x32, key=(0,42), partitionable scheme: bits(f) = o0^o1 of
// threefry2x32((0,42),(0,f)); uniform = bitcast((bits>>9)|0x3f800000)-1 < 0.8
// ---------------------------------------------------------------------------
__device__ __forceinline__ uint32_t rotl32(uint32_t x, int r) {
    return (x << r) | (x >> (32 - r));
}

__device__ __forceinline__ uint32_t threefry_bits(uint32_t f) {
    const uint32_t ks0 = 0u;
    const uint32_t ks1 = 42u;
    const uint32_t ks2 = 0x1BD11BDAu ^ 0u ^ 42u;
    uint32_t x0 = 0u + ks0;
    uint32_t x1 = f  + ks1;
#define TF_ROUND(r) { x0 += x1; x1 = rotl32(x1, (r)); x1 ^= x0; }
    TF_ROUND(13) TF_ROUND(15) TF_ROUND(26) TF_ROUND(6)
    x0 += ks1; x1 += ks2 + 1u;
    TF_ROUND(17) TF_ROUND(29) TF_ROUND(16) TF_ROUND(24)
    x0 += ks2; x1 += ks0 + 2u;
    TF_ROUND(13) TF_ROUND(15) TF_ROUND(26) TF_ROUND(6)
    x0 += ks0; x1 += ks1 + 3u;
    TF_ROUND(17) TF_ROUND(29) TF_ROUND(16) TF_ROUND(24)
    x0 += ks1; x1 += ks2 + 4u;
    TF_ROUND(13) TF_ROUND(15) TF_ROUND(26) TF_ROUND(6)
    x0 += ks2; x1 += ks0 + 5u;
#undef TF_ROUND
    return x0 ^ x1;
}

__device__ __forceinline__ bool dropout_keep(uint32_t f) {
    uint32_t bits = threefry_bits(f);
    float u = __uint_as_float((bits >> 9) | 0x3f800000u) - 1.0f;
    return u < 0.8f;
}

// ---------------------------------------------------------------------------
// 1. Bucket histogram via per-block LDS histograms (782 counters)
// ---------------------------------------------------------------------------
__global__ __launch_bounds__(256) void k_bhist(const int* __restrict__ dst,
                                               int* __restrict__ bcnt) {
    __shared__ int h[NBUCK];
    for (int i = threadIdx.x; i < NBUCK; i += 256) h[i] = 0;
    __syncthreads();
    const int stride = gridDim.x * 256;
    for (int e = blockIdx.x * 256 + threadIdx.x; e < N_EDGES; e += stride)
        atomicAdd(&h[dst[e] >> BUCK_BITS], 1);
    __syncthreads();
    for (int i = threadIdx.x; i < NBUCK; i += 256) {
        int v = h[i];
        if (v) atomicAdd(&bcnt[i], v);
    }
}

// ---------------------------------------------------------------------------
// 2. Scan of 782 bucket counts (single block); seed partition cursors
// ---------------------------------------------------------------------------
__global__ __launch_bounds__(1024) void k_bscan(const int* __restrict__ bcnt,
                                                int* __restrict__ boff,
                                                int* __restrict__ bcur) {
    __shared__ int lds[1024];
    const int t = threadIdx.x;
    int v = (t < NBUCK) ? bcnt[t] : 0;
    lds[t] = v;
    __syncthreads();
#pragma unroll
    for (int off = 1; off < 1024; off <<= 1) {
        int u = (t >= off) ? lds[t - off] : 0;
        __syncthreads();
        lds[t] += u;
        __syncthreads();
    }
    if (t < NBUCK) {
        int ex = lds[t] - v;
        boff[t] = ex;
        bcur[t] = ex;
    }
    if (t == 0) boff[NBUCK] = N_EDGES;
}

// ---------------------------------------------------------------------------
// 3. Partition edges into bucket windows; pack (dstlo<<17 | src) in u32.
//    Writes are localized to ~8 KB windows -> lines assemble in L2.
// ---------------------------------------------------------------------------
__global__ __launch_bounds__(256) void k_part(const int* __restrict__ src,
                                              const int* __restrict__ dst,
                                              int* __restrict__ bcur,
                                              uint32_t* __restrict__ part) {
    int e = blockIdx.x * 256 + threadIdx.x;
    if (e >= N_EDGES) return;
    int d = dst[e];
    int b = d >> BUCK_BITS;
    int pos = atomicAdd(&bcur[b], 1);
    part[pos] = ((uint32_t)(d & (BUCK_SZ - 1)) << 17) | (uint32_t)src[e];
}

// ---------------------------------------------------------------------------
// 4. Per-bucket node degree (LDS histogram) -> dinv
// ---------------------------------------------------------------------------
__global__ __launch_bounds__(256) void k_ndeg(const uint32_t* __restrict__ part,
                                              const int* __restrict__ boff,
                                              float* __restrict__ dinv) {
    __shared__ int cnt[BUCK_SZ];
    const int b = blockIdx.x;
    const int t = threadIdx.x;
    if (t < BUCK_SZ) cnt[t] = 0;
    __syncthreads();
    const int beg = boff[b], end = boff[b + 1];
    for (int j = beg + t; j < end; j += 256)
        atomicAdd(&cnt[(part[j] >> 17) & (BUCK_SZ - 1)], 1);
    __syncthreads();
    int node = b * BUCK_SZ + t;
    if (t < BUCK_SZ && node < N_NODES)
        dinv[node] = rsqrtf((float)(cnt[t] + 1));
}

// ---------------------------------------------------------------------------
// 5. h0s = (x @ W1) * dinv[row]
// ---------------------------------------------------------------------------
__global__ __launch_bounds__(256) void k_gemm1(const float* __restrict__ x,
                                               const float* __restrict__ W1,
                                               const float* __restrict__ dinv,
                                               float* __restrict__ h0s) {
    __shared__ __align__(16) float w1s[NFEAT * HIDDEN];
    __shared__ __align__(16) float xs[8 * NFEAT];
    const int tid = threadIdx.x;
    for (int i = tid; i < NFEAT * HIDDEN / 4; i += 256)
        ((float4*)w1s)[i] = ((const float4*)W1)[i];
    const int row0 = blockIdx.x * 8;
    const float4* xb = (const float4*)(x + (size_t)row0 * NFEAT);
    if (tid < 200) ((float4*)xs)[tid] = xb[tid];
    __syncthreads();
    const int r = tid >> 5, c = tid & 31;
    float acc = 0.0f;
#pragma unroll 4
    for (int k = 0; k < NFEAT; ++k)
        acc = fmaf(xs[r * NFEAT + k], w1s[k * HIDDEN + c], acc);
    int row = row0 + r;
    h0s[(size_t)row * HIDDEN + c] = acc * dinv[row];
}

// ---------------------------------------------------------------------------
// 6. Layer 1 fused, bucket-local: LDS accumulator [128][32], stream edges,
//    gather h0s rows, ds_add_f32 accumulate; epilogue does din/b1/ReLU/
//    dropout/W2-reduce and writes pre-scaled h2s.
// ---------------------------------------------------------------------------
__global__ __launch_bounds__(256) void k_l1(const uint32_t* __restrict__ part,
                                            const int* __restrict__ boff,
                                            const float* __restrict__ dinv,
                                            const float* __restrict__ h0s,
                                            const float* __restrict__ b1,
                                            const float* __restrict__ W2,
                                            float* __restrict__ h2s) {
    __shared__ float acc[BUCK_SZ * HIDDEN];   // 16 KB
    const int b = blockIdx.x;
    const int t = threadIdx.x;
    const int nbase = b * BUCK_SZ;
    // init with self-loop term (h0s already scaled by dinv[node])
    for (int i = t; i < BUCK_SZ * HIDDEN; i += 256) {
        int node = nbase + (i >> 5);
        acc[i] = (node < N_NODES) ? h0s[(size_t)nbase * HIDDEN + i] : 0.0f;
    }
    __syncthreads();
    const int g = t >> 5, c = t & 31;
    const int beg = boff[b], end = boff[b + 1];
    for (int j = beg + g; j < end; j += 8) {
        uint32_t v = part[j];
        int s  = v & 0x1FFFF;
        int dl = (v >> 17) & (BUCK_SZ - 1);
        atomicAdd(&acc[dl * HIDDEN + c], h0s[(size_t)s * HIDDEN + c]);
    }
    __syncthreads();
    // epilogue: 8 groups x 16 nodes
    for (int i = g; i < BUCK_SZ; i += 8) {
        int node = nbase + i;
        if (node >= N_NODES) continue;
        float din = dinv[node];
        float v = fmaxf(fmaf(acc[i * HIDDEN + c], din, b1[c]), 0.0f);
        v = dropout_keep((uint32_t)(node * HIDDEN + c)) ? v * 1.25f : 0.0f;
        float p0 = v * W2[c * 2 + 0];
        float p1 = v * W2[c * 2 + 1];
#pragma unroll
        for (int m = 16; m >= 1; m >>= 1) {
            p0 += __shfl_xor(p0, m);
            p1 += __shfl_xor(p1, m);
        }
        if (c == 0) {
            float2* o = (float2*)(h2s + (size_t)node * 2);
            *o = make_float2(p0 * din, p1 * din);
        }
    }
}

// ---------------------------------------------------------------------------
// 7. Layer 2 fused, bucket-local: LDS accumulator [128][2] + log_softmax.
// ---------------------------------------------------------------------------
__global__ __launch_bounds__(256) void k_l2(const uint32_t* __restrict__ part,
                                            const int* __restrict__ boff,
                                            const float* __restrict__ dinv,
                                            const float* __restrict__ h2s,
                                            const float* __restrict__ b2,
                                            float* __restrict__ out) {
    __shared__ float acc[BUCK_SZ * 2];
    const int b = blockIdx.x;
    const int t = threadIdx.x;
    const int nbase = b * BUCK_SZ;
    {   // init with self-loop term (h2s pre-scaled by dinv[node])
        int node = nbase + (t >> 1);
        acc[t] = (node < N_NODES) ? h2s[(size_t)nbase * 2 + t] : 0.0f;
    }
    __syncthreads();
    const int comp = t & 1;
    const int beg = boff[b], end = boff[b + 1];
    for (int j = beg + (t >> 1); j < end; j += 128) {
        uint32_t v = part[j];
        int s  = v & 0x1FFFF;
        int dl = (v >> 17) & (BUCK_SZ - 1);
        atomicAdd(&acc[dl * 2 + comp], h2s[(size_t)s * 2 + comp]);
    }
    __syncthreads();
    if (t < BUCK_SZ) {
        int node = nbase + t;
        if (node < N_NODES) {
            float din = dinv[node];
            float l0 = fmaf(acc[t * 2 + 0], din, b2[0]);
            float l1 = fmaf(acc[t * 2 + 1], din, b2[1]);
            float m = fmaxf(l0, l1);
            float lse = m + logf(expf(l0 - m) + expf(l1 - m));
            float2* o = (float2*)(out + (size_t)node * 2);
            *o = make_float2(l0 - lse, l1 - lse);
        }
    }
}

// ---------------------------------------------------------------------------
// Launch
// ---------------------------------------------------------------------------
static inline size_t align_up(size_t x) { return (x + 255) & ~(size_t)255; }

extern "C" void kernel_launch(void* const* d_in, const int* in_sizes, int n_in,
                              void* d_out, int out_size, void* d_ws, size_t ws_size,
                              hipStream_t stream) {
    (void)n_in; (void)in_sizes; (void)out_size; (void)ws_size;

    const float* x  = (const float*)d_in[0];
    const int*   ei = (const int*)d_in[1];
    const float* W1 = (const float*)d_in[2];
    const float* b1 = (const float*)d_in[3];
    const float* W2 = (const float*)d_in[4];
    const float* b2 = (const float*)d_in[5];
    float* out = (float*)d_out;

    const int* src = ei;
    const int* dst = ei + N_EDGES;

    char* w = (char*)d_ws;
    size_t off = 0;
    int*      bcnt = (int*)(w + off);      off += align_up((size_t)NBUCK * 4);
    int*      boff = (int*)(w + off);      off += align_up((size_t)(NBUCK + 1) * 4);
    int*      bcur = (int*)(w + off);      off += align_up((size_t)NBUCK * 4);
    float*    dinv = (float*)(w + off);    off += align_up((size_t)N_NODES * 4);
    uint32_t* part = (uint32_t*)(w + off); off += align_up((size_t)N_EDGES * 4);
    float*    h0s  = (float*)(w + off);    off += align_up((size_t)N_NODES * HIDDEN * 4);
    float*    h2s  = (float*)(w + off);    off += align_up((size_t)N_NODES * OUTC * 4);

    hipMemsetAsync(bcnt, 0, (size_t)NBUCK * 4, stream);

    const int B = 256;
    k_bhist<<<256, B, 0, stream>>>(dst, bcnt);
    k_bscan<<<1, 1024, 0, stream>>>(bcnt, boff, bcur);
    k_part <<<(N_EDGES + B - 1) / B, B, 0, stream>>>(src, dst, bcur, part);
    k_ndeg <<<NBUCK, B, 0, stream>>>(part, boff, dinv);
    k_gemm1<<<N_NODES / 8, B, 0, stream>>>(x, W1, dinv, h0s);
    k_l1   <<<NBUCK, B, 0, stream>>>(part, boff, dinv, h0s, b1, W2, h2s);
    k_l2   <<<NBUCK, B, 0, stream>>>(part, boff, dinv, h2s, b2, out);
}

// Round 6
// 530.379 us; speedup vs baseline: 1.6970x; 1.6970x over previous
//
#include <hip/hip_runtime.h>
#include <stdint.h>
#include <math.h>

#define N_NODES   100000
#define N_EDGES   1600000
#define NFEAT     100
#define HIDDEN    32
#define OUTC      2

#define BUCK_BITS 7
#define BUCK_SZ   128
#define NBUCK     782                       // ceil(100000/128)

#define PART_NB   256                       // partition blocks
#define PART_CHUNK ((N_EDGES + PART_NB - 1) / PART_NB)   // 6250

// ---------------------------------------------------------------------------
// JAX threefry2x32, key=(0,42), partitionable: bits(f) = o0^o1
// ---------------------------------------------------------------------------
__device__ __forceinline__ uint32_t rotl32(uint32_t x, int r) {
    return (x << r) | (x >> (32 - r));
}

__device__ __forceinline__ uint32_t threefry_bits(uint32_t f) {
    const uint32_t ks0 = 0u;
    const uint32_t ks1 = 42u;
    const uint32_t ks2 = 0x1BD11BDAu ^ 0u ^ 42u;
    uint32_t x0 = 0u + ks0;
    uint32_t x1 = f  + ks1;
#define TF_ROUND(r) { x0 += x1; x1 = rotl32(x1, (r)); x1 ^= x0; }
    TF_ROUND(13) TF_ROUND(15) TF_ROUND(26) TF_ROUND(6)
    x0 += ks1; x1 += ks2 + 1u;
    TF_ROUND(17) TF_ROUND(29) TF_ROUND(16) TF_ROUND(24)
    x0 += ks2; x1 += ks0 + 2u;
    TF_ROUND(13) TF_ROUND(15) TF_ROUND(26) TF_ROUND(6)
    x0 += ks0; x1 += ks1 + 3u;
    TF_ROUND(17) TF_ROUND(29) TF_ROUND(16) TF_ROUND(24)
    x0 += ks1; x1 += ks2 + 4u;
    TF_ROUND(13) TF_ROUND(15) TF_ROUND(26) TF_ROUND(6)
    x0 += ks2; x1 += ks0 + 5u;
#undef TF_ROUND
    return x0 ^ x1;
}

__device__ __forceinline__ bool dropout_keep(uint32_t f) {
    uint32_t bits = threefry_bits(f);
    float u = __uint_as_float((bits >> 9) | 0x3f800000u) - 1.0f;
    return u < 0.8f;
}

// ---------------------------------------------------------------------------
// 1. Bucket histogram via per-block LDS histograms
// ---------------------------------------------------------------------------
__global__ __launch_bounds__(256) void k_bhist(const int* __restrict__ dst,
                                               int* __restrict__ bcnt) {
    __shared__ int h[NBUCK];
    for (int i = threadIdx.x; i < NBUCK; i += 256) h[i] = 0;
    __syncthreads();
    const int stride = gridDim.x * 256;
    for (int e = blockIdx.x * 256 + threadIdx.x; e < N_EDGES; e += stride)
        atomicAdd(&h[dst[e] >> BUCK_BITS], 1);
    __syncthreads();
    for (int i = threadIdx.x; i < NBUCK; i += 256) {
        int v = h[i];
        if (v) atomicAdd(&bcnt[i], v);
    }
}

// ---------------------------------------------------------------------------
// 2. Scan of 782 bucket counts (single block); seed global cursors
// ---------------------------------------------------------------------------
__global__ __launch_bounds__(1024) void k_bscan(const int* __restrict__ bcnt,
                                                int* __restrict__ boff,
                                                int* __restrict__ bcur) {
    __shared__ int lds[1024];
    const int t = threadIdx.x;
    int v = (t < NBUCK) ? bcnt[t] : 0;
    lds[t] = v;
    __syncthreads();
#pragma unroll
    for (int off = 1; off < 1024; off <<= 1) {
        int u = (t >= off) ? lds[t - off] : 0;
        __syncthreads();
        lds[t] += u;
        __syncthreads();
    }
    if (t < NBUCK) {
        int ex = lds[t] - v;
        boff[t] = ex;
        bcur[t] = ex;
    }
    if (t == 0) boff[NBUCK] = N_EDGES;
}

// ---------------------------------------------------------------------------
// 3. Partition, block-aggregated reservation:
//    per-block LDS histogram -> ONE global atomic per (block,bucket) ->
//    LDS cursors assign positions. Global atomics: ~200k @ ~256/counter.
// ---------------------------------------------------------------------------
__global__ __launch_bounds__(1024) void k_part(const int* __restrict__ src,
                                               const int* __restrict__ dst,
                                               int* __restrict__ bcur,
                                               uint32_t* __restrict__ part) {
    __shared__ int hist[NBUCK];
    __shared__ int cur[NBUCK];
    const int t = threadIdx.x;
    const int base = blockIdx.x * PART_CHUNK;
    const int lim = min(base + PART_CHUNK, N_EDGES);
    if (t < NBUCK) hist[t] = 0;
    __syncthreads();
    for (int e = base + t; e < lim; e += 1024)
        atomicAdd(&hist[dst[e] >> BUCK_BITS], 1);
    __syncthreads();
    if (t < NBUCK) {
        int c = hist[t];
        cur[t] = c ? atomicAdd(&bcur[t], c) : 0;
    }
    __syncthreads();
    for (int e = base + t; e < lim; e += 1024) {
        int d = dst[e];
        int b = d >> BUCK_BITS;
        int pos = atomicAdd(&cur[b], 1);
        part[pos] = ((uint32_t)(d & (BUCK_SZ - 1)) << 17) | (uint32_t)src[e];
    }
}

// ---------------------------------------------------------------------------
// 4. Per-bucket node degree (LDS histogram) -> dinv
// ---------------------------------------------------------------------------
__global__ __launch_bounds__(256) void k_ndeg(const uint32_t* __restrict__ part,
                                              const int* __restrict__ boff,
                                              float* __restrict__ dinv) {
    __shared__ int cnt[BUCK_SZ];
    const int b = blockIdx.x;
    const int t = threadIdx.x;
    if (t < BUCK_SZ) cnt[t] = 0;
    __syncthreads();
    const int beg = boff[b], end = boff[b + 1];
    for (int j = beg + t; j < end; j += 256)
        atomicAdd(&cnt[(part[j] >> 17) & (BUCK_SZ - 1)], 1);
    __syncthreads();
    int node = b * BUCK_SZ + t;
    if (t < BUCK_SZ && node < N_NODES)
        dinv[node] = rsqrtf((float)(cnt[t] + 1));
}

// ---------------------------------------------------------------------------
// 5. h0s = (x @ W1) * dinv[row]
// ---------------------------------------------------------------------------
__global__ __launch_bounds__(256) void k_gemm1(const float* __restrict__ x,
                                               const float* __restrict__ W1,
                                               const float* __restrict__ dinv,
                                               float* __restrict__ h0s) {
    __shared__ __align__(16) float w1s[NFEAT * HIDDEN];
    __shared__ __align__(16) float xs[8 * NFEAT];
    const int tid = threadIdx.x;
    for (int i = tid; i < NFEAT * HIDDEN / 4; i += 256)
        ((float4*)w1s)[i] = ((const float4*)W1)[i];
    const int row0 = blockIdx.x * 8;
    const float4* xb = (const float4*)(x + (size_t)row0 * NFEAT);
    if (tid < 200) ((float4*)xs)[tid] = xb[tid];
    __syncthreads();
    const int r = tid >> 5, c = tid & 31;
    float acc = 0.0f;
#pragma unroll 4
    for (int k = 0; k < NFEAT; ++k)
        acc = fmaf(xs[r * NFEAT + k], w1s[k * HIDDEN + c], acc);
    int row = row0 + r;
    h0s[(size_t)row * HIDDEN + c] = acc * dinv[row];
}

// ---------------------------------------------------------------------------
// 6. Layer 1 fused, bucket-local. 512 threads = 16 groups of 32 lanes.
//    4x unrolled gather loop for memory-level parallelism.
// ---------------------------------------------------------------------------
#define L1_NG 16
__global__ __launch_bounds__(512) void k_l1(const uint32_t* __restrict__ part,
                                            const int* __restrict__ boff,
                                            const float* __restrict__ dinv,
                                            const float* __restrict__ h0s,
                                            const float* __restrict__ b1,
                                            const float* __restrict__ W2,
                                            float* __restrict__ h2s) {
    __shared__ float acc[BUCK_SZ * HIDDEN];   // 16 KB
    const int b = blockIdx.x;
    const int t = threadIdx.x;
    const int nbase = b * BUCK_SZ;
    for (int i = t; i < BUCK_SZ * HIDDEN; i += 512) {
        int node = nbase + (i >> 5);
        acc[i] = (node < N_NODES) ? h0s[(size_t)nbase * HIDDEN + i] : 0.0f;
    }
    __syncthreads();
    const int g = t >> 5, c = t & 31;
    const int beg = boff[b], end = boff[b + 1];
    int j = beg + g;
    for (; j + 3 * L1_NG < end; j += 4 * L1_NG) {
        uint32_t v0 = part[j];
        uint32_t v1 = part[j + L1_NG];
        uint32_t v2 = part[j + 2 * L1_NG];
        uint32_t v3 = part[j + 3 * L1_NG];
        float f0 = h0s[(size_t)(v0 & 0x1FFFF) * HIDDEN + c];
        float f1 = h0s[(size_t)(v1 & 0x1FFFF) * HIDDEN + c];
        float f2 = h0s[(size_t)(v2 & 0x1FFFF) * HIDDEN + c];
        float f3 = h0s[(size_t)(v3 & 0x1FFFF) * HIDDEN + c];
        atomicAdd(&acc[((v0 >> 17) & (BUCK_SZ - 1)) * HIDDEN + c], f0);
        atomicAdd(&acc[((v1 >> 17) & (BUCK_SZ - 1)) * HIDDEN + c], f1);
        atomicAdd(&acc[((v2 >> 17) & (BUCK_SZ - 1)) * HIDDEN + c], f2);
        atomicAdd(&acc[((v3 >> 17) & (BUCK_SZ - 1)) * HIDDEN + c], f3);
    }
    for (; j < end; j += L1_NG) {
        uint32_t v = part[j];
        atomicAdd(&acc[((v >> 17) & (BUCK_SZ - 1)) * HIDDEN + c],
                  h0s[(size_t)(v & 0x1FFFF) * HIDDEN + c]);
    }
    __syncthreads();
    for (int i = g; i < BUCK_SZ; i += L1_NG) {
        int node = nbase + i;
        if (node >= N_NODES) continue;
        float din = dinv[node];
        float v = fmaxf(fmaf(acc[i * HIDDEN + c], din, b1[c]), 0.0f);
        v = dropout_keep((uint32_t)(node * HIDDEN + c)) ? v * 1.25f : 0.0f;
        float p0 = v * W2[c * 2 + 0];
        float p1 = v * W2[c * 2 + 1];
#pragma unroll
        for (int m = 16; m >= 1; m >>= 1) {
            p0 += __shfl_xor(p0, m);
            p1 += __shfl_xor(p1, m);
        }
        if (c == 0) {
            float2* o = (float2*)(h2s + (size_t)node * 2);
            *o = make_float2(p0 * din, p1 * din);
        }
    }
}

// ---------------------------------------------------------------------------
// 7. Layer 2 fused, bucket-local; 2x unrolled.
// ---------------------------------------------------------------------------
__global__ __launch_bounds__(256) void k_l2(const uint32_t* __restrict__ part,
                                            const int* __restrict__ boff,
                                            const float* __restrict__ dinv,
                                            const float* __restrict__ h2s,
                                            const float* __restrict__ b2,
                                            float* __restrict__ out) {
    __shared__ float acc[BUCK_SZ * 2];
    const int b = blockIdx.x;
    const int t = threadIdx.x;
    const int nbase = b * BUCK_SZ;
    {
        int node = nbase + (t >> 1);
        acc[t] = (node < N_NODES) ? h2s[(size_t)nbase * 2 + t] : 0.0f;
    }
    __syncthreads();
    const int comp = t & 1;
    const int w = t >> 1;   // 128 edge workers
    const int beg = boff[b], end = boff[b + 1];
    int j = beg + w;
    for (; j + 128 < end; j += 256) {
        uint32_t v0 = part[j];
        uint32_t v1 = part[j + 128];
        float f0 = h2s[(size_t)(v0 & 0x1FFFF) * 2 + comp];
        float f1 = h2s[(size_t)(v1 & 0x1FFFF) * 2 + comp];
        atomicAdd(&acc[((v0 >> 17) & (BUCK_SZ - 1)) * 2 + comp], f0);
        atomicAdd(&acc[((v1 >> 17) & (BUCK_SZ - 1)) * 2 + comp], f1);
    }
    for (; j < end; j += 128) {
        uint32_t v = part[j];
        atomicAdd(&acc[((v >> 17) & (BUCK_SZ - 1)) * 2 + comp],
                  h2s[(size_t)(v & 0x1FFFF) * 2 + comp]);
    }
    __syncthreads();
    if (t < BUCK_SZ) {
        int node = nbase + t;
        if (node < N_NODES) {
            float din = dinv[node];
            float l0 = fmaf(acc[t * 2 + 0], din, b2[0]);
            float l1 = fmaf(acc[t * 2 + 1], din, b2[1]);
            float m = fmaxf(l0, l1);
            float lse = m + logf(expf(l0 - m) + expf(l1 - m));
            float2* o = (float2*)(out + (size_t)node * 2);
            *o = make_float2(l0 - lse, l1 - lse);
        }
    }
}

// ---------------------------------------------------------------------------
// Launch
// ---------------------------------------------------------------------------
static inline size_t align_up(size_t x) { return (x + 255) & ~(size_t)255; }

extern "C" void kernel_launch(void* const* d_in, const int* in_sizes, int n_in,
                              void* d_out, int out_size, void* d_ws, size_t ws_size,
                              hipStream_t stream) {
    (void)n_in; (void)in_sizes; (void)out_size; (void)ws_size;

    const float* x  = (const float*)d_in[0];
    const int*   ei = (const int*)d_in[1];
    const float* W1 = (const float*)d_in[2];
    const float* b1 = (const float*)d_in[3];
    const float* W2 = (const float*)d_in[4];
    const float* b2 = (const float*)d_in[5];
    float* out = (float*)d_out;

    const int* src = ei;
    const int* dst = ei + N_EDGES;

    char* w = (char*)d_ws;
    size_t off = 0;
    int*      bcnt = (int*)(w + off);      off += align_up((size_t)NBUCK * 4);
    int*      boff = (int*)(w + off);      off += align_up((size_t)(NBUCK + 1) * 4);
    int*      bcur = (int*)(w + off);      off += align_up((size_t)NBUCK * 4);
    float*    dinv = (float*)(w + off);    off += align_up((size_t)N_NODES * 4);
    uint32_t* part = (uint32_t*)(w + off); off += align_up((size_t)N_EDGES * 4);
    float*    h0s  = (float*)(w + off);    off += align_up((size_t)N_NODES * HIDDEN * 4);
    float*    h2s  = (float*)(w + off);    off += align_up((size_t)N_NODES * OUTC * 4);

    hipMemsetAsync(bcnt, 0, (size_t)NBUCK * 4, stream);

    const int B = 256;
    k_bhist<<<256, B, 0, stream>>>(dst, bcnt);
    k_bscan<<<1, 1024, 0, stream>>>(bcnt, boff, bcur);
    k_part <<<PART_NB, 1024, 0, stream>>>(src, dst, bcur, part);
    k_ndeg <<<NBUCK, B, 0, stream>>>(part, boff, dinv);
    k_gemm1<<<N_NODES / 8, B, 0, stream>>>(x, W1, dinv, h0s);
    k_l1   <<<NBUCK, 512, 0, stream>>>(part, boff, dinv, h0s, b1, W2, h2s);
    k_l2   <<<NBUCK, B, 0, stream>>>(part, boff, dinv, h2s, b2, out);
}

// Round 7
// 220.704 us; speedup vs baseline: 4.0781x; 2.4031x over previous
//
#include <hip/hip_runtime.h>
#include <stdint.h>
#include <math.h>

#define N_NODES   100000
#define N_EDGES   1600000
#define NFEAT     100
#define HIDDEN    32
#define OUTC      2

#define BUCK_BITS 7
#define BUCK_SZ   128
#define NBUCK     782                       // ceil(100000/128)

#define PART_NB   256
#define PART_CHUNK ((N_EDGES + PART_NB - 1) / PART_NB)   // 6250

// ---------------------------------------------------------------------------
// JAX threefry2x32, key=(0,42), partitionable: bits(f) = o0^o1
// ---------------------------------------------------------------------------
__device__ __forceinline__ uint32_t rotl32(uint32_t x, int r) {
    return (x << r) | (x >> (32 - r));
}

__device__ __forceinline__ uint32_t threefry_bits(uint32_t f) {
    const uint32_t ks0 = 0u;
    const uint32_t ks1 = 42u;
    const uint32_t ks2 = 0x1BD11BDAu ^ 0u ^ 42u;
    uint32_t x0 = 0u + ks0;
    uint32_t x1 = f  + ks1;
#define TF_ROUND(r) { x0 += x1; x1 = rotl32(x1, (r)); x1 ^= x0; }
    TF_ROUND(13) TF_ROUND(15) TF_ROUND(26) TF_ROUND(6)
    x0 += ks1; x1 += ks2 + 1u;
    TF_ROUND(17) TF_ROUND(29) TF_ROUND(16) TF_ROUND(24)
    x0 += ks2; x1 += ks0 + 2u;
    TF_ROUND(13) TF_ROUND(15) TF_ROUND(26) TF_ROUND(6)
    x0 += ks0; x1 += ks1 + 3u;
    TF_ROUND(17) TF_ROUND(29) TF_ROUND(16) TF_ROUND(24)
    x0 += ks1; x1 += ks2 + 4u;
    TF_ROUND(13) TF_ROUND(15) TF_ROUND(26) TF_ROUND(6)
    x0 += ks2; x1 += ks0 + 5u;
#undef TF_ROUND
    return x0 ^ x1;
}

__device__ __forceinline__ bool dropout_keep(uint32_t f) {
    uint32_t bits = threefry_bits(f);
    float u = __uint_as_float((bits >> 9) | 0x3f800000u) - 1.0f;
    return u < 0.8f;
}

// ---------------------------------------------------------------------------
// 1. Bucket histogram via per-block LDS histograms
// ---------------------------------------------------------------------------
__global__ __launch_bounds__(256) void k_bhist(const int* __restrict__ dst,
                                               int* __restrict__ bcnt) {
    __shared__ int h[NBUCK];
    for (int i = threadIdx.x; i < NBUCK; i += 256) h[i] = 0;
    __syncthreads();
    const int stride = gridDim.x * 256;
    for (int e = blockIdx.x * 256 + threadIdx.x; e < N_EDGES; e += stride)
        atomicAdd(&h[dst[e] >> BUCK_BITS], 1);
    __syncthreads();
    for (int i = threadIdx.x; i < NBUCK; i += 256) {
        int v = h[i];
        if (v) atomicAdd(&bcnt[i], v);
    }
}

// ---------------------------------------------------------------------------
// 2. Scan of 782 bucket counts (single block); seed global cursors
// ---------------------------------------------------------------------------
__global__ __launch_bounds__(1024) void k_bscan(const int* __restrict__ bcnt,
                                                int* __restrict__ boff,
                                                int* __restrict__ bcur) {
    __shared__ int lds[1024];
    const int t = threadIdx.x;
    int v = (t < NBUCK) ? bcnt[t] : 0;
    lds[t] = v;
    __syncthreads();
#pragma unroll
    for (int off = 1; off < 1024; off <<= 1) {
        int u = (t >= off) ? lds[t - off] : 0;
        __syncthreads();
        lds[t] += u;
        __syncthreads();
    }
    if (t < NBUCK) {
        int ex = lds[t] - v;
        boff[t] = ex;
        bcur[t] = ex;
    }
    if (t == 0) boff[NBUCK] = N_EDGES;
}

// ---------------------------------------------------------------------------
// 3. Partition with block-aggregated reservation (fast since R6)
// ---------------------------------------------------------------------------
__global__ __launch_bounds__(1024) void k_part(const int* __restrict__ src,
                                               const int* __restrict__ dst,
                                               int* __restrict__ bcur,
                                               uint32_t* __restrict__ part) {
    __shared__ int hist[NBUCK];
    __shared__ int cur[NBUCK];
    const int t = threadIdx.x;
    const int base = blockIdx.x * PART_CHUNK;
    const int lim = min(base + PART_CHUNK, N_EDGES);
    if (t < NBUCK) hist[t] = 0;
    __syncthreads();
    for (int e = base + t; e < lim; e += 1024)
        atomicAdd(&hist[dst[e] >> BUCK_BITS], 1);
    __syncthreads();
    if (t < NBUCK) {
        int c = hist[t];
        cur[t] = c ? atomicAdd(&bcur[t], c) : 0;
    }
    __syncthreads();
    for (int e = base + t; e < lim; e += 1024) {
        int d = dst[e];
        int b = d >> BUCK_BITS;
        int pos = atomicAdd(&cur[b], 1);
        part[pos] = ((uint32_t)(d & (BUCK_SZ - 1)) << 17) | (uint32_t)src[e];
    }
}

// ---------------------------------------------------------------------------
// 4. Per-bucket counting sort -> true CSR (csr_src), rowptr, dinv.
//    All writes stay in the bucket's contiguous ~8 KB window.
// ---------------------------------------------------------------------------
__global__ __launch_bounds__(256) void k_sort(const uint32_t* __restrict__ part,
                                              const int* __restrict__ boff,
                                              int* __restrict__ csr_src,
                                              int* __restrict__ rowptr,
                                              float* __restrict__ dinv) {
    __shared__ int cnt[BUCK_SZ];
    __shared__ int pref[BUCK_SZ];
    __shared__ int cur[BUCK_SZ];
    const int b = blockIdx.x;
    const int t = threadIdx.x;
    const int nbase = b * BUCK_SZ;
    const int bb = boff[b], be = boff[b + 1];
    if (t < BUCK_SZ) cnt[t] = 0;
    __syncthreads();
    for (int j = bb + t; j < be; j += 256)
        atomicAdd(&cnt[(part[j] >> 17) & (BUCK_SZ - 1)], 1);
    __syncthreads();
    if (t < BUCK_SZ) pref[t] = cnt[t];
    __syncthreads();
#pragma unroll
    for (int off = 1; off < BUCK_SZ; off <<= 1) {
        int v = (t >= off && t < BUCK_SZ) ? pref[t - off] : 0;
        __syncthreads();
        if (t < BUCK_SZ) pref[t] += v;
        __syncthreads();
    }
    if (t < BUCK_SZ) {
        int ex = pref[t] - cnt[t];
        cur[t] = ex;
        int node = nbase + t;
        if (node < N_NODES) {
            rowptr[node] = bb + ex;
            dinv[node] = rsqrtf((float)(cnt[t] + 1));
        }
    }
    if (b == NBUCK - 1 && t == 0) rowptr[N_NODES] = N_EDGES;
    __syncthreads();
    for (int j = bb + t; j < be; j += 256) {
        uint32_t v = part[j];
        int dl = (v >> 17) & (BUCK_SZ - 1);
        int pos = bb + atomicAdd(&cur[dl], 1);
        csr_src[pos] = (int)(v & 0x1FFFF);
    }
}

// ---------------------------------------------------------------------------
// 5. h0s = (x @ W1) * dinv[row]
// ---------------------------------------------------------------------------
__global__ __launch_bounds__(256) void k_gemm1(const float* __restrict__ x,
                                               const float* __restrict__ W1,
                                               const float* __restrict__ dinv,
                                               float* __restrict__ h0s) {
    __shared__ __align__(16) float w1s[NFEAT * HIDDEN];
    __shared__ __align__(16) float xs[8 * NFEAT];
    const int tid = threadIdx.x;
    for (int i = tid; i < NFEAT * HIDDEN / 4; i += 256)
        ((float4*)w1s)[i] = ((const float4*)W1)[i];
    const int row0 = blockIdx.x * 8;
    const float4* xb = (const float4*)(x + (size_t)row0 * NFEAT);
    if (tid < 200) ((float4*)xs)[tid] = xb[tid];
    __syncthreads();
    const int r = tid >> 5, c = tid & 31;
    float acc = 0.0f;
#pragma unroll 4
    for (int k = 0; k < NFEAT; ++k)
        acc = fmaf(xs[r * NFEAT + k], w1s[k * HIDDEN + c], acc);
    int row = row0 + r;
    h0s[(size_t)row * HIDDEN + c] = acc * dinv[row];
}

// ---------------------------------------------------------------------------
// 6. Layer 1: register-pull CSR aggregation, 32 lanes/node, 4x unrolled
//    gathers (4 independent loads in flight, register accumulators).
//    + b1 + ReLU + dropout + @W2 reduce; writes pre-scaled h2s.
// ---------------------------------------------------------------------------
__global__ __launch_bounds__(256) void k_l1(const int* __restrict__ rowptr,
                                            const int* __restrict__ csr_src,
                                            const float* __restrict__ dinv,
                                            const float* __restrict__ h0s,
                                            const float* __restrict__ b1,
                                            const float* __restrict__ W2,
                                            float* __restrict__ h2s) {
    int t = blockIdx.x * 256 + threadIdx.x;
    int n = t >> 5;
    int c = t & 31;
    if (n >= N_NODES) return;
    float a0 = h0s[(size_t)n * HIDDEN + c];   // self loop (pre-scaled)
    float a1 = 0.0f, a2 = 0.0f, a3 = 0.0f;
    int j = rowptr[n];
    const int end = rowptr[n + 1];
    for (; j + 3 < end; j += 4) {
        int s0 = csr_src[j], s1 = csr_src[j + 1];
        int s2 = csr_src[j + 2], s3 = csr_src[j + 3];
        a0 += h0s[(size_t)s0 * HIDDEN + c];
        a1 += h0s[(size_t)s1 * HIDDEN + c];
        a2 += h0s[(size_t)s2 * HIDDEN + c];
        a3 += h0s[(size_t)s3 * HIDDEN + c];
    }
    for (; j < end; ++j) a0 += h0s[(size_t)csr_src[j] * HIDDEN + c];
    float acc = (a0 + a1) + (a2 + a3);
    float din = dinv[n];
    float v = fmaxf(fmaf(acc, din, b1[c]), 0.0f);
    v = dropout_keep((uint32_t)(n * HIDDEN + c)) ? v * 1.25f : 0.0f;
    float p0 = v * W2[c * 2 + 0];
    float p1 = v * W2[c * 2 + 1];
#pragma unroll
    for (int m = 16; m >= 1; m >>= 1) {
        p0 += __shfl_xor(p0, m);
        p1 += __shfl_xor(p1, m);
    }
    if (c == 0) {
        float2* o = (float2*)(h2s + (size_t)n * 2);
        *o = make_float2(p0 * din, p1 * din);
    }
}

// ---------------------------------------------------------------------------
// 7. Layer 2: register-pull CSR, 8 lanes/node, 2x unrolled float2 gathers,
//    + b2 + log_softmax.
// ---------------------------------------------------------------------------
__global__ __launch_bounds__(256) void k_l2(const int* __restrict__ rowptr,
                                            const int* __restrict__ csr_src,
                                            const float* __restrict__ dinv,
                                            const float* __restrict__ h2s,
                                            const float* __restrict__ b2,
                                            float* __restrict__ out) {
    int t = blockIdx.x * 256 + threadIdx.x;
    int n = t >> 3;
    int l = t & 7;
    if (n >= N_NODES) return;
    float acc0 = 0.0f, acc1 = 0.0f;
    float bcc0 = 0.0f, bcc1 = 0.0f;
    if (l == 0) {
        float2 hn = ((const float2*)h2s)[n];
        acc0 = hn.x; acc1 = hn.y;
    }
    int j = rowptr[n] + l;
    const int end = rowptr[n + 1];
    for (; j + 8 < end; j += 16) {
        float2 h0v = ((const float2*)h2s)[csr_src[j]];
        float2 h1v = ((const float2*)h2s)[csr_src[j + 8]];
        acc0 += h0v.x; acc1 += h0v.y;
        bcc0 += h1v.x; bcc1 += h1v.y;
    }
    if (j < end) {
        float2 hv = ((const float2*)h2s)[csr_src[j]];
        acc0 += hv.x; acc1 += hv.y;
    }
    acc0 += bcc0; acc1 += bcc1;
#pragma unroll
    for (int m = 4; m >= 1; m >>= 1) {
        acc0 += __shfl_xor(acc0, m);
        acc1 += __shfl_xor(acc1, m);
    }
    if (l == 0) {
        float din = dinv[n];
        float l0 = fmaf(acc0, din, b2[0]);
        float l1 = fmaf(acc1, din, b2[1]);
        float m = fmaxf(l0, l1);
        float lse = m + logf(expf(l0 - m) + expf(l1 - m));
        float2* o = (float2*)(out + (size_t)n * 2);
        *o = make_float2(l0 - lse, l1 - lse);
    }
}

// ---------------------------------------------------------------------------
// Launch
// ---------------------------------------------------------------------------
static inline size_t align_up(size_t x) { return (x + 255) & ~(size_t)255; }

extern "C" void kernel_launch(void* const* d_in, const int* in_sizes, int n_in,
                              void* d_out, int out_size, void* d_ws, size_t ws_size,
                              hipStream_t stream) {
    (void)n_in; (void)in_sizes; (void)out_size; (void)ws_size;

    const float* x  = (const float*)d_in[0];
    const int*   ei = (const int*)d_in[1];
    const float* W1 = (const float*)d_in[2];
    const float* b1 = (const float*)d_in[3];
    const float* W2 = (const float*)d_in[4];
    const float* b2 = (const float*)d_in[5];
    float* out = (float*)d_out;

    const int* src = ei;
    const int* dst = ei + N_EDGES;

    char* w = (char*)d_ws;
    size_t off = 0;
    int*      bcnt   = (int*)(w + off);      off += align_up((size_t)NBUCK * 4);
    int*      boff   = (int*)(w + off);      off += align_up((size_t)(NBUCK + 1) * 4);
    int*      bcur   = (int*)(w + off);      off += align_up((size_t)NBUCK * 4);
    int*      rowptr = (int*)(w + off);      off += align_up((size_t)(N_NODES + 1) * 4);
    float*    dinv   = (float*)(w + off);    off += align_up((size_t)N_NODES * 4);
    uint32_t* part   = (uint32_t*)(w + off); off += align_up((size_t)N_EDGES * 4);
    int*      csr    = (int*)(w + off);      off += align_up((size_t)N_EDGES * 4);
    float*    h0s    = (float*)(w + off);    off += align_up((size_t)N_NODES * HIDDEN * 4);
    float*    h2s    = (float*)(w + off);    off += align_up((size_t)N_NODES * OUTC * 4);

    hipMemsetAsync(bcnt, 0, (size_t)NBUCK * 4, stream);

    const int B = 256;
    k_bhist<<<256, B, 0, stream>>>(dst, bcnt);
    k_bscan<<<1, 1024, 0, stream>>>(bcnt, boff, bcur);
    k_part <<<PART_NB, 1024, 0, stream>>>(src, dst, bcur, part);
    k_sort <<<NBUCK, B, 0, stream>>>(part, boff, csr, rowptr, dinv);
    k_gemm1<<<N_NODES / 8, B, 0, stream>>>(x, W1, dinv, h0s);
    k_l1   <<<(N_NODES * HIDDEN + B - 1) / B, B, 0, stream>>>(rowptr, csr, dinv, h0s, b1, W2, h2s);
    k_l2   <<<(N_NODES * 8 + B - 1) / B, B, 0, stream>>>(rowptr, csr, dinv, h2s, b2, out);
}